// Round 7
// baseline (644.311 us; speedup 1.0000x reference)
//
#include <hip/hip_runtime.h>
#include <stdint.h>

#define S_  8
#define D_  2048
#define B_  2
#define N_  1024
#define SD_ 16384
#define JP_ 11    // 11 pairs of bf16 weight columns (22 columns)
#define NP_ 2     // n-values per block

typedef float f32x4 __attribute__((ext_vector_type(4)));   // native vec for nontemporal store

__device__ __forceinline__ unsigned pack_bf16_rne(float a, float b) {
    unsigned ua = __float_as_uint(a);
    unsigned ub = __float_as_uint(b);
    ua += 0x7FFFu + ((ua >> 16) & 1u);   // round-to-nearest-even
    ub += 0x7FFFu + ((ub >> 16) & 1u);
    return (ua >> 16) | (ub & 0xFFFF0000u);
}

// ---------------------------------------------------------------------------
// prep: Wp[(s*11+jp)*2048 + d] = bf16pair( (gamma+1)*w[2jp], (gamma+1)*w[2jp+1] )
// ---------------------------------------------------------------------------
extern "C" __global__ void krom_prep(const float* __restrict__ gamma,
                                     const float* __restrict__ Wa,
                                     const float* __restrict__ Wb,
                                     unsigned* __restrict__ Wp)
{
    const int u = blockIdx.x * 256 + threadIdx.x;   // = (s*11+jp)*2048 + d
    if (u >= JP_ * SD_) return;
    const int sj = u >> 11;          // s*11 + jp
    const int d  = u & 2047;
    const int s  = sj / JP_;
    const int jp = sj - s * JP_;
    const int i  = (s << 11) + d;    // row into (SD_) weight matrices
    const float g = gamma[i] + 1.0f;
    float w0, w1;
    if (jp < 7) {
        w0 = Wa[i * 14 + 2 * jp];
        w1 = Wa[i * 14 + 2 * jp + 1];
    } else {
        const int j = jp - 7;
        w0 = Wb[i * 8 + 2 * j];
        w1 = Wb[i * 8 + 2 * j + 1];
    }
    Wp[u] = pack_bf16_rne(g * w0, g * w1);
}

// ---------------------------------------------------------------------------
// Fused kernel, NP=2, latency-oriented rebuild:
//  - s-loop FULLY UNROLLED (compile-time addresses, scheduler freedom)
//  - r loads for s+1 issued BEFORE s's fmaf chain (hand prefetch; r is the
//    ~900-cyc HBM-latency load, Wp is ~200-cyc L2-hit)
//  - phase 2 hoists all 8 r loads per n ahead of the fmaf chain
//  - launch_bounds(512,4): VGPR cap 128 so unrolling can't spill
// Round-6 lesson: NP=4 halved Wp ops but halved wave slots (VGPR 128) - a
// wash.  Keep VGPR low, maximize in-flight loads per SIMD instead.
// ---------------------------------------------------------------------------
extern "C" __global__ void __launch_bounds__(512, 4)
krom_fused(const float* __restrict__ res,
           const unsigned* __restrict__ Wp,
           const float* __restrict__ sa,     // static_alpha[14]
           const float* __restrict__ pre_s,  // pre_branch_scale[1]
           const float* __restrict__ res_s,  // residual_scale[1]
           const float* __restrict__ sb,     // static_beta[8]
           const float* __restrict__ hps,    // h_post_scale[1]
           float* __restrict__ out)
{
    const int tid = threadIdx.x;
    const int blk = blockIdx.x;           // 0..1023 = b*512 + pair
    const int b   = blk >> 9;
    const int n0  = (blk & 511) * NP_;
    const int d0  = tid * 4;              // 4 d-values per thread

    // ---- phase 1: matvec + ssq ------------------------------------------
    float acc0[23], acc1[23];
#pragma unroll
    for (int j = 0; j < 23; ++j) { acc0[j] = 0.0f; acc1[j] = 0.0f; }

    const float* prb = res + (((size_t)(b * S_) * N_ + n0) * D_ + d0);
    // preload s=0
    float4 va = *reinterpret_cast<const float4*>(prb);
    float4 vb = *reinterpret_cast<const float4*>(prb + D_);

#pragma unroll
    for (int s = 0; s < S_; ++s) {
        // prefetch s+1's r (HBM latency) before this iteration's compute
        float4 na = va, nb = vb;
        if (s + 1 < S_) {
            const float* pn = prb + (size_t)(s + 1) * N_ * D_;
            na = *reinterpret_cast<const float4*>(pn);
            nb = *reinterpret_cast<const float4*>(pn + D_);
        }
        const float ra[4] = {va.x, va.y, va.z, va.w};
        const float rb[4] = {vb.x, vb.y, vb.z, vb.w};
#pragma unroll
        for (int k = 0; k < 4; ++k) {
            acc0[22] = fmaf(ra[k], ra[k], acc0[22]);
            acc1[22] = fmaf(rb[k], rb[k], acc1[22]);
        }
        const unsigned* pw = Wp + ((s * JP_) << 11) + d0;
#pragma unroll
        for (int jp = 0; jp < JP_; ++jp) {
            const uint4 u = *reinterpret_cast<const uint4*>(pw + (jp << 11));
            const unsigned uu[4] = {u.x, u.y, u.z, u.w};
#pragma unroll
            for (int k = 0; k < 4; ++k) {
                const float w0 = __uint_as_float(uu[k] << 16);
                const float w1 = __uint_as_float(uu[k] & 0xFFFF0000u);
                acc0[2 * jp]     = fmaf(ra[k], w0, acc0[2 * jp]);
                acc0[2 * jp + 1] = fmaf(ra[k], w1, acc0[2 * jp + 1]);
                acc1[2 * jp]     = fmaf(rb[k], w0, acc1[2 * jp]);
                acc1[2 * jp + 1] = fmaf(rb[k], w1, acc1[2 * jp + 1]);
            }
        }
        va = na; vb = nb;
    }

    // ---- block-wide reduction of 2x23 partials (8 waves) ----------------
    __shared__ float red[8][NP_][23];
    __shared__ float fin[NP_][23];
    const int wave = tid >> 6, lane = tid & 63;
#pragma unroll
    for (int j = 0; j < 23; ++j) {
        float v0 = acc0[j], v1 = acc1[j];
#pragma unroll
        for (int m = 1; m < 64; m <<= 1) {
            v0 += __shfl_xor(v0, m, 64);
            v1 += __shfl_xor(v1, m, 64);
        }
        if (lane == 0) { red[wave][0][j] = v0; red[wave][1][j] = v1; }
    }
    __syncthreads();
    if (tid < NP_ * 23) {
        const int n = tid / 23, j = tid - n * 23;
        float v = 0.0f;
#pragma unroll
        for (int w = 0; w < 8; ++w) v += red[w][n][j];
        fin[n][j] = v;
    }
    __syncthreads();

    // ---- tiny epilogue math (2 threads, one per n) ----------------------
    __shared__ float wpre[NP_][S_], bet[NP_][S_], pk3[NP_][3];
    if (tid < NP_) {
        const int n = tid;
        const float inv   = rsqrtf(fmaxf(fin[n][22], 1e-24f));
        const float scale = inv * 128.0f;    // sqrt(16384)
        float c[22];
#pragma unroll
        for (int j = 0; j < 22; ++j) c[j] = fin[n][j] * scale;
        const float ps = pre_s[0], rs = res_s[0], hs = hps[0];
        float lg[8], mx = -1e30f;
#pragma unroll
        for (int s = 0; s < 8; ++s) { lg[s] = ps * c[s] + sa[s]; mx = fmaxf(mx, lg[s]); }
        float sum = 0.0f;
#pragma unroll
        for (int s = 0; s < 8; ++s) { lg[s] = expf(lg[s] - mx); sum += lg[s]; }
        const float rsum = 1.0f / sum;
#pragma unroll
        for (int s = 0; s < 8; ++s) wpre[n][s] = lg[s] * rsum;
#pragma unroll
        for (int k = 0; k < 3; ++k) {
            float a0 = rs * c[8 + 2 * k] + sa[8 + 2 * k];
            float a1 = rs * c[9 + 2 * k] + sa[9 + 2 * k];
            pk3[n][k] = 1.0f / (1.0f + expf(a1 - a0));
        }
#pragma unroll
        for (int t = 0; t < 8; ++t)
            bet[n][t] = 1.0f / (1.0f + expf(-(hs * c[14 + t] + sb[t])));
    }
    __syncthreads();

    // ---- M[s][t] = hres[s][t] + beta[t]*w_pre[s] -> LDS -----------------
    __shared__ float Ms[NP_][S_][S_];
    if (tid < NP_ * 64) {
        const int n = tid >> 6, e = tid & 63, s = e >> 3, t = e & 7;
        float h = 1.0f;
#pragma unroll
        for (int k = 0; k < 3; ++k) {
            int sbit = (s >> (2 - k)) & 1, tbit = (t >> (2 - k)) & 1;
            float pk = pk3[n][k];
            h *= (sbit == tbit) ? pk : (1.0f - pk);
        }
        Ms[n][s][t] = h + bet[n][t] * wpre[n][s];
    }
    __syncthreads();

    // ---- phase 2: out[(b*8+t), n, d] = sum_s M[s][t] * r[s][d] ----------
    // All 8 r loads issued before the fmaf chain (they're L2/L3-hot but
    // still ~200 cyc); nontemporal stores keep Wp resident in L2.
#pragma unroll
    for (int n = 0; n < NP_; ++n) {
        float4 rv[S_];
#pragma unroll
        for (int s = 0; s < S_; ++s)
            rv[s] = *reinterpret_cast<const float4*>(
                res + (((size_t)(b * S_ + s) * N_ + (n0 + n)) * D_ + d0));

        float o[8][4];
#pragma unroll
        for (int t = 0; t < 8; ++t)
#pragma unroll
            for (int k = 0; k < 4; ++k) o[t][k] = 0.0f;

#pragma unroll
        for (int s = 0; s < S_; ++s) {
            const float4 m0 = *reinterpret_cast<const float4*>(&Ms[n][s][0]);
            const float4 m1 = *reinterpret_cast<const float4*>(&Ms[n][s][4]);
            const float4 r4 = rv[s];
            o[0][0] = fmaf(m0.x, r4.x, o[0][0]); o[0][1] = fmaf(m0.x, r4.y, o[0][1]);
            o[0][2] = fmaf(m0.x, r4.z, o[0][2]); o[0][3] = fmaf(m0.x, r4.w, o[0][3]);
            o[1][0] = fmaf(m0.y, r4.x, o[1][0]); o[1][1] = fmaf(m0.y, r4.y, o[1][1]);
            o[1][2] = fmaf(m0.y, r4.z, o[1][2]); o[1][3] = fmaf(m0.y, r4.w, o[1][3]);
            o[2][0] = fmaf(m0.z, r4.x, o[2][0]); o[2][1] = fmaf(m0.z, r4.y, o[2][1]);
            o[2][2] = fmaf(m0.z, r4.z, o[2][2]); o[2][3] = fmaf(m0.z, r4.w, o[2][3]);
            o[3][0] = fmaf(m0.w, r4.x, o[3][0]); o[3][1] = fmaf(m0.w, r4.y, o[3][1]);
            o[3][2] = fmaf(m0.w, r4.z, o[3][2]); o[3][3] = fmaf(m0.w, r4.w, o[3][3]);
            o[4][0] = fmaf(m1.x, r4.x, o[4][0]); o[4][1] = fmaf(m1.x, r4.y, o[4][1]);
            o[4][2] = fmaf(m1.x, r4.z, o[4][2]); o[4][3] = fmaf(m1.x, r4.w, o[4][3]);
            o[5][0] = fmaf(m1.y, r4.x, o[5][0]); o[5][1] = fmaf(m1.y, r4.y, o[5][1]);
            o[5][2] = fmaf(m1.y, r4.z, o[5][2]); o[5][3] = fmaf(m1.y, r4.w, o[5][3]);
            o[6][0] = fmaf(m1.z, r4.x, o[6][0]); o[6][1] = fmaf(m1.z, r4.y, o[6][1]);
            o[6][2] = fmaf(m1.z, r4.z, o[6][2]); o[6][3] = fmaf(m1.z, r4.w, o[6][3]);
            o[7][0] = fmaf(m1.w, r4.x, o[7][0]); o[7][1] = fmaf(m1.w, r4.y, o[7][1]);
            o[7][2] = fmaf(m1.w, r4.z, o[7][2]); o[7][3] = fmaf(m1.w, r4.w, o[7][3]);
        }
#pragma unroll
        for (int t = 0; t < 8; ++t) {
            float* po = out + (((size_t)(b * S_ + t) * N_ + (n0 + n)) * D_ + d0);
            f32x4 ov = {o[t][0], o[t][1], o[t][2], o[t][3]};
            __builtin_nontemporal_store(ov, reinterpret_cast<f32x4*>(po));
        }
    }
}

extern "C" void kernel_launch(void* const* d_in, const int* in_sizes, int n_in,
                              void* d_out, int out_size, void* d_ws, size_t ws_size,
                              hipStream_t stream)
{
    (void)in_sizes; (void)n_in; (void)out_size; (void)ws_size;
    // input order per setup_inputs(): residuals, gamma, static_alpha, W_alpha,
    // pre_branch_scale, residual_scale, static_beta, W_beta, h_post_scale
    const float* residuals = (const float*)d_in[0];
    const float* gamma     = (const float*)d_in[1];
    const float* sa        = (const float*)d_in[2];
    const float* Wa        = (const float*)d_in[3];
    const float* pre_s     = (const float*)d_in[4];
    const float* res_s     = (const float*)d_in[5];
    const float* sb        = (const float*)d_in[6];
    const float* Wb        = (const float*)d_in[7];
    const float* hps       = (const float*)d_in[8];

    // workspace layout: Wp [0, 720896) only.
    unsigned* Wp = (unsigned*)d_ws;

    hipLaunchKernelGGL(krom_prep, dim3((JP_ * SD_ + 255) / 256), dim3(256), 0, stream,
                       gamma, Wa, Wb, Wp);
    hipLaunchKernelGGL(krom_fused, dim3(B_ * N_ / NP_), dim3(512), 0, stream,
                       residuals, Wp, sa, pre_s, res_s, sb, hps, (float*)d_out);
}

// Round 8
// 280.948 us; speedup vs baseline: 2.2933x; 2.2933x over previous
//
#include <hip/hip_runtime.h>
#include <stdint.h>

#define S_  8
#define D_  2048
#define B_  2
#define N_  1024
#define SD_ 16384
#define JP_ 11    // 11 pairs of bf16 weight columns (22 columns)
#define NP_ 2     // n-values per block

typedef float f32x4 __attribute__((ext_vector_type(4)));   // native vec for nontemporal store

__device__ __forceinline__ unsigned pack_bf16_rne(float a, float b) {
    unsigned ua = __float_as_uint(a);
    unsigned ub = __float_as_uint(b);
    ua += 0x7FFFu + ((ua >> 16) & 1u);   // round-to-nearest-even
    ub += 0x7FFFu + ((ub >> 16) & 1u);
    return (ua >> 16) | (ub & 0xFFFF0000u);
}

// ---------------------------------------------------------------------------
// prep: Wp[(s*11+jp)*2048 + d] = bf16pair( (gamma+1)*w[2jp], (gamma+1)*w[2jp+1] )
// ---------------------------------------------------------------------------
extern "C" __global__ void krom_prep(const float* __restrict__ gamma,
                                     const float* __restrict__ Wa,
                                     const float* __restrict__ Wb,
                                     unsigned* __restrict__ Wp)
{
    const int u = blockIdx.x * 256 + threadIdx.x;   // = (s*11+jp)*2048 + d
    if (u >= JP_ * SD_) return;
    const int sj = u >> 11;          // s*11 + jp
    const int d  = u & 2047;
    const int s  = sj / JP_;
    const int jp = sj - s * JP_;
    const int i  = (s << 11) + d;    // row into (SD_) weight matrices
    const float g = gamma[i] + 1.0f;
    float w0, w1;
    if (jp < 7) {
        w0 = Wa[i * 14 + 2 * jp];
        w1 = Wa[i * 14 + 2 * jp + 1];
    } else {
        const int j = jp - 7;
        w0 = Wb[i * 8 + 2 * j];
        w1 = Wb[i * 8 + 2 * j + 1];
    }
    Wp[u] = pack_bf16_rne(g * w0, g * w1);
}

// ---------------------------------------------------------------------------
// Fused kernel, NP=2, software-pipelined phase 1:
//   per s-iter (ROLLED loop -- round 4's proven non-spilling shape):
//     1) batch-issue all 11 Wp uint4 loads into named regs u0..u10
//     2) issue next-s r prefetch (na/nb)      <- AFTER Wp: vmcnt is FIFO,
//        so consuming Wp never drains the prefetch
//     3) compute (ssq + 176 fmaf) on the CURRENT va/vb
//   The ~900-cyc HBM r-latency is overlapped with a full s-iteration.
// launch_bounds(512,2): no forced occupancy clamp (round-7 spill lesson).
// ---------------------------------------------------------------------------
extern "C" __global__ void __launch_bounds__(512, 2)
krom_fused(const float* __restrict__ res,
           const unsigned* __restrict__ Wp,
           const float* __restrict__ sa,     // static_alpha[14]
           const float* __restrict__ pre_s,  // pre_branch_scale[1]
           const float* __restrict__ res_s,  // residual_scale[1]
           const float* __restrict__ sb,     // static_beta[8]
           const float* __restrict__ hps,    // h_post_scale[1]
           float* __restrict__ out)
{
    const int tid = threadIdx.x;
    const int blk = blockIdx.x;           // 0..1023 = b*512 + pair
    const int b   = blk >> 9;
    const int n0  = (blk & 511) * NP_;
    const int d0  = tid * 4;              // 4 d-values per thread

    // ---- phase 1: matvec + ssq ------------------------------------------
    float acc0[23], acc1[23];
#pragma unroll
    for (int j = 0; j < 23; ++j) { acc0[j] = 0.0f; acc1[j] = 0.0f; }

    const float* prb = res + (((size_t)(b * S_) * N_ + n0) * D_ + d0);
    float4 va = *reinterpret_cast<const float4*>(prb);
    float4 vb = *reinterpret_cast<const float4*>(prb + D_);

    for (int s = 0; s < S_; ++s) {        // ROLLED
        // (1) batch-issue the 11 Wp loads for this s
        const unsigned* pw = Wp + ((s * JP_) << 11) + d0;
        const uint4 u0  = *reinterpret_cast<const uint4*>(pw);
        const uint4 u1  = *reinterpret_cast<const uint4*>(pw + (1 << 11));
        const uint4 u2  = *reinterpret_cast<const uint4*>(pw + (2 << 11));
        const uint4 u3  = *reinterpret_cast<const uint4*>(pw + (3 << 11));
        const uint4 u4  = *reinterpret_cast<const uint4*>(pw + (4 << 11));
        const uint4 u5  = *reinterpret_cast<const uint4*>(pw + (5 << 11));
        const uint4 u6  = *reinterpret_cast<const uint4*>(pw + (6 << 11));
        const uint4 u7  = *reinterpret_cast<const uint4*>(pw + (7 << 11));
        const uint4 u8  = *reinterpret_cast<const uint4*>(pw + (8 << 11));
        const uint4 u9  = *reinterpret_cast<const uint4*>(pw + (9 << 11));
        const uint4 u10 = *reinterpret_cast<const uint4*>(pw + (10 << 11));

        // (2) prefetch next-s r (issued after Wp; stays in flight during compute)
        float4 na = va, nb = vb;
        if (s + 1 < S_) {
            const float* pn = prb + (size_t)(s + 1) * N_ * D_;
            na = *reinterpret_cast<const float4*>(pn);
            nb = *reinterpret_cast<const float4*>(pn + D_);
        }

        // (3) compute on current va/vb
        const float ra[4] = {va.x, va.y, va.z, va.w};
        const float rb[4] = {vb.x, vb.y, vb.z, vb.w};
#pragma unroll
        for (int k = 0; k < 4; ++k) {
            acc0[22] = fmaf(ra[k], ra[k], acc0[22]);
            acc1[22] = fmaf(rb[k], rb[k], acc1[22]);
        }
#define JPBLK(U, JPI)                                                         \
        {                                                                     \
            const unsigned uu[4] = {U.x, U.y, U.z, U.w};                      \
            _Pragma("unroll")                                                 \
            for (int k = 0; k < 4; ++k) {                                     \
                const float w0 = __uint_as_float(uu[k] << 16);                \
                const float w1 = __uint_as_float(uu[k] & 0xFFFF0000u);        \
                acc0[2 * JPI]     = fmaf(ra[k], w0, acc0[2 * JPI]);           \
                acc0[2 * JPI + 1] = fmaf(ra[k], w1, acc0[2 * JPI + 1]);       \
                acc1[2 * JPI]     = fmaf(rb[k], w0, acc1[2 * JPI]);           \
                acc1[2 * JPI + 1] = fmaf(rb[k], w1, acc1[2 * JPI + 1]);       \
            }                                                                 \
        }
        JPBLK(u0, 0)  JPBLK(u1, 1)  JPBLK(u2, 2)  JPBLK(u3, 3)
        JPBLK(u4, 4)  JPBLK(u5, 5)  JPBLK(u6, 6)  JPBLK(u7, 7)
        JPBLK(u8, 8)  JPBLK(u9, 9)  JPBLK(u10, 10)
#undef JPBLK
        va = na; vb = nb;
    }

    // ---- block-wide reduction of 2x23 partials (8 waves) ----------------
    __shared__ float red[8][NP_][23];
    __shared__ float fin[NP_][23];
    const int wave = tid >> 6, lane = tid & 63;
#pragma unroll
    for (int j = 0; j < 23; ++j) {
        float v0 = acc0[j], v1 = acc1[j];
#pragma unroll
        for (int m = 1; m < 64; m <<= 1) {
            v0 += __shfl_xor(v0, m, 64);
            v1 += __shfl_xor(v1, m, 64);
        }
        if (lane == 0) { red[wave][0][j] = v0; red[wave][1][j] = v1; }
    }
    __syncthreads();
    if (tid < NP_ * 23) {
        const int n = tid / 23, j = tid - n * 23;
        float v = 0.0f;
#pragma unroll
        for (int w = 0; w < 8; ++w) v += red[w][n][j];
        fin[n][j] = v;
    }
    __syncthreads();

    // ---- tiny epilogue math (2 threads, one per n) ----------------------
    __shared__ float wpre[NP_][S_], bet[NP_][S_], pk3[NP_][3];
    if (tid < NP_) {
        const int n = tid;
        const float inv   = rsqrtf(fmaxf(fin[n][22], 1e-24f));
        const float scale = inv * 128.0f;    // sqrt(16384)
        float c[22];
#pragma unroll
        for (int j = 0; j < 22; ++j) c[j] = fin[n][j] * scale;
        const float ps = pre_s[0], rs = res_s[0], hs = hps[0];
        float lg[8], mx = -1e30f;
#pragma unroll
        for (int s = 0; s < 8; ++s) { lg[s] = ps * c[s] + sa[s]; mx = fmaxf(mx, lg[s]); }
        float sum = 0.0f;
#pragma unroll
        for (int s = 0; s < 8; ++s) { lg[s] = expf(lg[s] - mx); sum += lg[s]; }
        const float rsum = 1.0f / sum;
#pragma unroll
        for (int s = 0; s < 8; ++s) wpre[n][s] = lg[s] * rsum;
#pragma unroll
        for (int k = 0; k < 3; ++k) {
            float a0 = rs * c[8 + 2 * k] + sa[8 + 2 * k];
            float a1 = rs * c[9 + 2 * k] + sa[9 + 2 * k];
            pk3[n][k] = 1.0f / (1.0f + expf(a1 - a0));
        }
#pragma unroll
        for (int t = 0; t < 8; ++t)
            bet[n][t] = 1.0f / (1.0f + expf(-(hs * c[14 + t] + sb[t])));
    }
    __syncthreads();

    // ---- M[s][t] = hres[s][t] + beta[t]*w_pre[s] -> LDS -----------------
    __shared__ float Ms[NP_][S_][S_];
    if (tid < NP_ * 64) {
        const int n = tid >> 6, e = tid & 63, s = e >> 3, t = e & 7;
        float h = 1.0f;
#pragma unroll
        for (int k = 0; k < 3; ++k) {
            int sbit = (s >> (2 - k)) & 1, tbit = (t >> (2 - k)) & 1;
            float pk = pk3[n][k];
            h *= (sbit == tbit) ? pk : (1.0f - pk);
        }
        Ms[n][s][t] = h + bet[n][t] * wpre[n][s];
    }
    __syncthreads();

    // ---- phase 2: out[(b*8+t), n, d] = sum_s M[s][t] * r[s][d] ----------
    // All 8 r loads issued up front (L2/L3-hot); nontemporal stores keep
    // Wp + r resident in L2.
#pragma unroll
    for (int n = 0; n < NP_; ++n) {
        float4 rv[S_];
#pragma unroll
        for (int s = 0; s < S_; ++s)
            rv[s] = *reinterpret_cast<const float4*>(
                res + (((size_t)(b * S_ + s) * N_ + (n0 + n)) * D_ + d0));

        float o[8][4];
#pragma unroll
        for (int t = 0; t < 8; ++t)
#pragma unroll
            for (int k = 0; k < 4; ++k) o[t][k] = 0.0f;

#pragma unroll
        for (int s = 0; s < S_; ++s) {
            const float4 m0 = *reinterpret_cast<const float4*>(&Ms[n][s][0]);
            const float4 m1 = *reinterpret_cast<const float4*>(&Ms[n][s][4]);
            const float4 r4 = rv[s];
            o[0][0] = fmaf(m0.x, r4.x, o[0][0]); o[0][1] = fmaf(m0.x, r4.y, o[0][1]);
            o[0][2] = fmaf(m0.x, r4.z, o[0][2]); o[0][3] = fmaf(m0.x, r4.w, o[0][3]);
            o[1][0] = fmaf(m0.y, r4.x, o[1][0]); o[1][1] = fmaf(m0.y, r4.y, o[1][1]);
            o[1][2] = fmaf(m0.y, r4.z, o[1][2]); o[1][3] = fmaf(m0.y, r4.w, o[1][3]);
            o[2][0] = fmaf(m0.z, r4.x, o[2][0]); o[2][1] = fmaf(m0.z, r4.y, o[2][1]);
            o[2][2] = fmaf(m0.z, r4.z, o[2][2]); o[2][3] = fmaf(m0.z, r4.w, o[2][3]);
            o[3][0] = fmaf(m0.w, r4.x, o[3][0]); o[3][1] = fmaf(m0.w, r4.y, o[3][1]);
            o[3][2] = fmaf(m0.w, r4.z, o[3][2]); o[3][3] = fmaf(m0.w, r4.w, o[3][3]);
            o[4][0] = fmaf(m1.x, r4.x, o[4][0]); o[4][1] = fmaf(m1.x, r4.y, o[4][1]);
            o[4][2] = fmaf(m1.x, r4.z, o[4][2]); o[4][3] = fmaf(m1.x, r4.w, o[4][3]);
            o[5][0] = fmaf(m1.y, r4.x, o[5][0]); o[5][1] = fmaf(m1.y, r4.y, o[5][1]);
            o[5][2] = fmaf(m1.y, r4.z, o[5][2]); o[5][3] = fmaf(m1.y, r4.w, o[5][3]);
            o[6][0] = fmaf(m1.z, r4.x, o[6][0]); o[6][1] = fmaf(m1.z, r4.y, o[6][1]);
            o[6][2] = fmaf(m1.z, r4.z, o[6][2]); o[6][3] = fmaf(m1.z, r4.w, o[6][3]);
            o[7][0] = fmaf(m1.w, r4.x, o[7][0]); o[7][1] = fmaf(m1.w, r4.y, o[7][1]);
            o[7][2] = fmaf(m1.w, r4.z, o[7][2]); o[7][3] = fmaf(m1.w, r4.w, o[7][3]);
        }
#pragma unroll
        for (int t = 0; t < 8; ++t) {
            float* po = out + (((size_t)(b * S_ + t) * N_ + (n0 + n)) * D_ + d0);
            f32x4 ov = {o[t][0], o[t][1], o[t][2], o[t][3]};
            __builtin_nontemporal_store(ov, reinterpret_cast<f32x4*>(po));
        }
    }
}

extern "C" void kernel_launch(void* const* d_in, const int* in_sizes, int n_in,
                              void* d_out, int out_size, void* d_ws, size_t ws_size,
                              hipStream_t stream)
{
    (void)in_sizes; (void)n_in; (void)out_size; (void)ws_size;
    // input order per setup_inputs(): residuals, gamma, static_alpha, W_alpha,
    // pre_branch_scale, residual_scale, static_beta, W_beta, h_post_scale
    const float* residuals = (const float*)d_in[0];
    const float* gamma     = (const float*)d_in[1];
    const float* sa        = (const float*)d_in[2];
    const float* Wa        = (const float*)d_in[3];
    const float* pre_s     = (const float*)d_in[4];
    const float* res_s     = (const float*)d_in[5];
    const float* sb        = (const float*)d_in[6];
    const float* Wb        = (const float*)d_in[7];
    const float* hps       = (const float*)d_in[8];

    // workspace layout: Wp [0, 720896) only.
    unsigned* Wp = (unsigned*)d_ws;

    hipLaunchKernelGGL(krom_prep, dim3((JP_ * SD_ + 255) / 256), dim3(256), 0, stream,
                       gamma, Wa, Wb, Wp);
    hipLaunchKernelGGL(krom_fused, dim3(B_ * N_ / NP_), dim3(512), 0, stream,
                       residuals, Wp, sa, pre_s, res_s, sb, hps, (float*)d_out);
}